// Round 8
// baseline (315.336 us; speedup 1.0000x reference)
//
#include <hip/hip_runtime.h>
#include <hip/hip_bf16.h>

// MechanismGrabber: B=2,S=4096,D=128,M=64. Outputs: integrated [8192,128] f32, vp [8192] f32.
// R8: kmech rebuilt for MFMA-bound regime: 128-token tiles (L2 traffic 256->128 MB),
// 8 waves = 2 e-16cols x 4 m-quarters, x from swizzled LDS (read 1x per 4-m group),
// FA/FB group ping-pong (16 B-loads in flight under 128 MFMAs), 2-barrier partial combine.
// kselect/kinteg/kprep as R7; single sel buffer; sbias folded into kmech acc init.

typedef __bf16 bf16_t;
typedef __bf16 bf16x8 __attribute__((ext_vector_type(8)));
typedef float  f32x4  __attribute__((ext_vector_type(4)));

// ws layout (bytes)
#define WS_WTT      0u          // bf16 [m][ks(4)][e(128)][g(4)][j(8)] frag-major Wt^T, 2 MB
#define WS_W1T      2097152u    // bf16 [256][256]
#define WS_W2T      2228224u    // bf16 [64][256]
#define WS_OT       2260992u    // bf16 [64][64]
#define WS_WG       2269184u    // bf16 [64][128]
#define WS_U        2285568u    // bf16 [64][128]
#define WS_CVEC     2301952u    // f32  [64]
#define WS_BCT      2302208u    // bf16 [128 e][64 m]
#define WS_WIT      2318592u    // bf16 [128][256]
#define WS_WT       2384128u    // f32  [64 m][8192 tok] (w transposed), 2 MB
#define WS_SBIAS    4481280u    // f32  [8192][128], 4 MB
#define WS_SEL      8675584u    // f32  [8192][128], 4 MB

#define VP_OFF 1048576

__device__ __forceinline__ f32x4 mfma16(bf16x8 a, bf16x8 b, f32x4 c) {
  return __builtin_amdgcn_mfma_f32_16x16x32_bf16(a, b, c, 0, 0, 0);
}

__device__ __forceinline__ float erf_fast(float x) {
  float ax = fabsf(x);
  float t = 1.0f / (1.0f + 0.3275911f * ax);
  float p = t * (0.254829592f + t * (-0.284496736f + t * (1.421413741f +
            t * (-1.453152027f + t * 1.061405429f))));
  float y = 1.0f - p * __expf(-ax * ax);
  return copysignf(y, x);
}
__device__ __forceinline__ float gelu_fast(float v) {
  return 0.5f * v * (1.0f + erf_fast(v * 0.70710678118654752f));
}
__device__ __forceinline__ float tanh_fast(float x) {
  float xc = fminf(fmaxf(x, -15.f), 15.f);
  float e = __expf(2.0f * xc);
  return (e - 1.0f) / (e + 1.0f);
}
__device__ __forceinline__ float sigmoidf_(float v) {
  return 1.0f / (1.0f + __expf(-v));
}

__device__ __forceinline__ bf16x8 cvt8(float4 v0, float4 v1) {
  bf16x8 a;
  a[0] = (bf16_t)v0.x; a[1] = (bf16_t)v0.y; a[2] = (bf16_t)v0.z; a[3] = (bf16_t)v0.w;
  a[4] = (bf16_t)v1.x; a[5] = (bf16_t)v1.y; a[6] = (bf16_t)v1.z; a[7] = (bf16_t)v1.w;
  return a;
}

// ---------------------------------------------------------------- kernel P
__global__ __launch_bounds__(256) void kprep(
    const float* __restrict__ Wt, const float* __restrict__ bt,
    const float* __restrict__ ch, const float* __restrict__ Wg,
    const float* __restrict__ Wv, const float* __restrict__ bv,
    const float* __restrict__ O, const float* __restrict__ W1,
    const float* __restrict__ W2, const float* __restrict__ Wi,
    char* __restrict__ ws)
{
  const int bid = blockIdx.x, tid = threadIdx.x;
  if (bid < 128) {
    const int m = bid >> 1, half = bid & 1;
    const float* wtm = Wt + m * 16384;
    bf16_t* wtt = (bf16_t*)(ws + WS_WTT) + m * 16384;
    const int ks = half * 2 + (tid >> 7), e = tid & 127;
    bf16_t tmp[32];
    #pragma unroll
    for (int dd = 0; dd < 32; ++dd)
      tmp[dd] = (bf16_t)wtm[(ks * 32 + dd) * 128 + e];
    bf16_t* dst = wtt + ks * 4096 + e * 32;
    #pragma unroll
    for (int g = 0; g < 4; ++g)
      *(bf16x8*)(dst + g * 8) = *(const bf16x8*)(tmp + g * 8);
  } else if (bid < 144) {
    int base = (bid - 128) * 256 + tid;
    int k = base >> 4, c0 = (base & 15) * 16;
    bf16_t* o = (bf16_t*)(ws + WS_W1T);
    #pragma unroll
    for (int j = 0; j < 16; ++j) o[(c0 + j) * 256 + k] = (bf16_t)W1[k * 256 + c0 + j];
  } else if (bid < 146) {
    int base = (bid - 144) * 256 + tid;
    int k = base >> 1, c0 = (base & 1) * 32;
    bf16_t* o = (bf16_t*)(ws + WS_W2T);
    #pragma unroll
    for (int j = 0; j < 32; ++j) o[(c0 + j) * 256 + k] = (bf16_t)W2[k * 64 + c0 + j];
  } else if (bid == 146) {
    int k = tid >> 2, c0 = (tid & 3) * 16;
    bf16_t* o = (bf16_t*)(ws + WS_OT);
    #pragma unroll
    for (int j = 0; j < 16; ++j) o[(c0 + j) * 64 + k] = (bf16_t)O[k * 64 + c0 + j];
  } else if (bid == 147) {
    bf16_t* o = (bf16_t*)(ws + WS_WG);
    #pragma unroll
    for (int j = 0; j < 32; ++j) o[tid * 32 + j] = (bf16_t)Wg[tid * 32 + j];
  } else if (bid == 148) {
    bf16_t* o = (bf16_t*)(ws + WS_BCT);
    #pragma unroll
    for (int i = 0; i < 4; ++i) {
      int task = tid + i * 256;
      int m = task >> 4, e0 = (task & 15) * 8;
      #pragma unroll
      for (int j = 0; j < 8; ++j)
        o[(e0 + j) * 64 + m] = (bf16_t)(bt[m * 128 + e0 + j] + ch[m * 128 + e0 + j]);
    }
  } else if (bid < 153) {
    int base = (bid - 149) * 256 + tid;
    int k = base >> 2, c0 = (base & 3) * 32;
    bf16_t* o = (bf16_t*)(ws + WS_WIT);
    #pragma unroll
    for (int j = 0; j < 32; ++j) o[(c0 + j) * 256 + k] = (bf16_t)Wi[k * 128 + c0 + j];
  } else if (bid < 185) {
    int task = (bid - 153) * 256 + tid;   // u[m][d]
    int m = task >> 7, d = task & 127;
    const float4* wp = (const float4*)(Wt + m * 16384 + d * 128);
    const float4* vp = (const float4*)(Wv + m * 128);
    float s = 0.f;
    #pragma unroll
    for (int i = 0; i < 32; ++i) {
      float4 a = wp[i], b = vp[i];
      s += a.x * b.x + a.y * b.y + a.z * b.z + a.w * b.w;
    }
    ((bf16_t*)(ws + WS_U))[m * 128 + d] = (bf16_t)s;
  } else {
    if (tid < 64) {
      int m = tid;
      const float4* bp = (const float4*)(bt + m * 128);
      const float4* cp = (const float4*)(ch + m * 128);
      const float4* vp = (const float4*)(Wv + m * 128);
      float s = bv[m];
      #pragma unroll
      for (int i = 0; i < 32; ++i) {
        float4 a = bp[i], c = cp[i], b = vp[i];
        s += (a.x + c.x) * b.x + (a.y + c.y) * b.y + (a.z + c.z) * b.z + (a.w + c.w) * b.w;
      }
      ((float*)(ws + WS_CVEC))[m] = s;
    }
  }
}

// ---------------------------------------------------------------- kernel S (selector)
__global__ __launch_bounds__(256) void kselect(
    const float* __restrict__ x, const float* __restrict__ ctx,
    const float* __restrict__ b1, const float* __restrict__ b2,
    const float* __restrict__ bg,
    char* __restrict__ ws, float* __restrict__ out)
{
  __shared__ char sm[43008];
  bf16_t* hL      = (bf16_t*)sm;               // [32][256] swz, 16 KB
  float*  scoresL = (float*)(sm + 16384);      // [32][64], 8 KB
  float*  wLT     = (float*)(sm + 24576);      // [64 m][36] f32, 9.2 KB
  bf16_t* scbL    = (bf16_t*)(sm + 33792);     // [32][64] swz, 4 KB
  bf16_t* wbL     = (bf16_t*)(sm + 37888);     // [32][64] swz, 4 KB
  float*  vpL     = (float*)(sm + 41984);      // [32][4]

  const int tid = threadIdx.x;
  const int lane = tid & 63, wq = tid >> 6;
  const int tb = blockIdx.x * 32;
  const int lr = lane & 15, lg = lane >> 4;
  const int lk = lg * 8, lj4 = lg * 4;

  const bf16_t* W1t = (const bf16_t*)(ws + WS_W1T);
  const bf16_t* W2t = (const bf16_t*)(ws + WS_W2T);
  const bf16_t* Ot  = (const bf16_t*)(ws + WS_OT);
  const bf16_t* Wgb = (const bf16_t*)(ws + WS_WG);
  const bf16_t* Ub  = (const bf16_t*)(ws + WS_U);
  const float*  cv  = (const float*)(ws + WS_CVEC);
  const bf16_t* bct = (const bf16_t*)(ws + WS_BCT);
  float* wT    = (float*)(ws + WS_WT);
  float* sbOut = (float*)(ws + WS_SBIAS);

  bf16x8 aX[2][4];
  #pragma unroll
  for (int rg = 0; rg < 2; ++rg) {
    const float* xr = x + (tb + rg * 16 + lr) * 128;
    #pragma unroll
    for (int ks = 0; ks < 4; ++ks)
      aX[rg][ks] = cvt8(*(const float4*)(xr + ks * 32 + lk),
                        *(const float4*)(xr + ks * 32 + lk + 4));
  }

  // GEMM1 -> gelu -> hL
  {
    f32x4 a1[4][2] = {{{0,0,0,0},{0,0,0,0}},{{0,0,0,0},{0,0,0,0}},
                      {{0,0,0,0},{0,0,0,0}},{{0,0,0,0},{0,0,0,0}}};
    #pragma unroll
    for (int ks = 0; ks < 8; ++ks) {
      bf16x8 af[2];
      if (ks < 4) {
        af[0] = aX[0][ks]; af[1] = aX[1][ks];
      } else {
        #pragma unroll
        for (int rg = 0; rg < 2; ++rg) {
          const float* cr = ctx + (tb + rg * 16 + lr) * 128 + (ks - 4) * 32 + lk;
          af[rg] = cvt8(*(const float4*)cr, *(const float4*)(cr + 4));
        }
      }
      #pragma unroll
      for (int cg = 0; cg < 4; ++cg) {
        bf16x8 b = *(const bf16x8*)(W1t + (wq * 64 + cg * 16 + lr) * 256 + ks * 32 + lk);
        a1[cg][0] = mfma16(af[0], b, a1[cg][0]);
        a1[cg][1] = mfma16(af[1], b, a1[cg][1]);
      }
    }
    #pragma unroll
    for (int cg = 0; cg < 4; ++cg) {
      int c = wq * 64 + cg * 16 + lr;
      float bb = b1[c];
      #pragma unroll
      for (int rg = 0; rg < 2; ++rg)
        #pragma unroll
        for (int j = 0; j < 4; ++j) {
          int r = rg * 16 + lj4 + j;
          float v = gelu_fast(a1[cg][rg][j] + bb);
          *(bf16_t*)((char*)hL + ((r * 512 + c * 2) ^ ((r & 7) << 4))) = (bf16_t)v;
        }
    }
  }
  __syncthreads();

  // GEMM2 -> logits
  {
    int c = wq * 16 + lr;
    f32x4 l[2] = {{0,0,0,0},{0,0,0,0}};
    #pragma unroll
    for (int ks = 0; ks < 8; ++ks) {
      int k0 = ks * 32 + lk;
      bf16x8 b = *(const bf16x8*)(W2t + c * 256 + k0);
      #pragma unroll
      for (int rg = 0; rg < 2; ++rg) {
        int r = rg * 16 + lr;
        bf16x8 a = *(const bf16x8*)((char*)hL + ((r * 512 + k0 * 2) ^ ((r & 7) << 4)));
        l[rg] = mfma16(a, b, l[rg]);
      }
    }
    float bb = b2[c];
    #pragma unroll
    for (int rg = 0; rg < 2; ++rg)
      #pragma unroll
      for (int j = 0; j < 4; ++j)
        scoresL[(rg * 16 + lj4 + j) * 64 + c] = l[rg][j] + bb;
  }
  __syncthreads();

  // softmax
  {
    int row = tid >> 3, i = tid & 7;
    float v[8];
    #pragma unroll
    for (int j = 0; j < 8; ++j) v[j] = scoresL[row * 64 + i * 8 + j];
    float mx = v[0];
    #pragma unroll
    for (int j = 1; j < 8; ++j) mx = fmaxf(mx, v[j]);
    mx = fmaxf(mx, __shfl_xor(mx, 1));
    mx = fmaxf(mx, __shfl_xor(mx, 2));
    mx = fmaxf(mx, __shfl_xor(mx, 4));
    float sum = 0.f;
    #pragma unroll
    for (int j = 0; j < 8; ++j) { v[j] = __expf(v[j] - mx); sum += v[j]; }
    sum += __shfl_xor(sum, 1);
    sum += __shfl_xor(sum, 2);
    sum += __shfl_xor(sum, 4);
    float inv = 1.0f / sum;
    #pragma unroll
    for (int j = 0; j < 8; ++j) {
      float s = v[j] * inv;
      int cc = i * 8 + j;
      scoresL[row * 64 + cc] = s;
      *(bf16_t*)((char*)scbL + ((row * 128 + cc * 2) ^ ((row & 7) << 4))) = (bf16_t)s;
    }
  }
  __syncthreads();

  // gates / timing / victory / w
  {
    const int c = wq * 16 + lr;
    f32x4 g[2] = {{0,0,0,0},{0,0,0,0}};
    #pragma unroll
    for (int ks = 0; ks < 2; ++ks) {
      int k0 = ks * 32 + lk;
      bf16x8 b = *(const bf16x8*)(Ot + c * 64 + k0);
      #pragma unroll
      for (int rg = 0; rg < 2; ++rg) {
        int r = rg * 16 + lr;
        bf16x8 a = *(const bf16x8*)((char*)scbL + ((r * 128 + k0 * 2) ^ ((r & 7) << 4)));
        g[rg] = mfma16(a, b, g[rg]);
      }
    }
    f32x4 t[2] = {{0,0,0,0},{0,0,0,0}};
    f32x4 v[2] = {{0,0,0,0},{0,0,0,0}};
    #pragma unroll
    for (int ks = 0; ks < 4; ++ks) {
      bf16x8 bT = *(const bf16x8*)(Wgb + c * 128 + ks * 32 + lk);
      bf16x8 bV = *(const bf16x8*)(Ub  + c * 128 + ks * 32 + lk);
      #pragma unroll
      for (int rg = 0; rg < 2; ++rg) {
        t[rg] = mfma16(aX[rg][ks], bT, t[rg]);
        v[rg] = mfma16(aX[rg][ks], bV, v[rg]);
      }
    }
    float bgc = bg[c], cvc = cv[c];
    #pragma unroll
    for (int rg = 0; rg < 2; ++rg)
      #pragma unroll
      for (int j = 0; j < 4; ++j) {
        int r = rg * 16 + lj4 + j;
        float gate = 1.0f + tanh_fast(g[rg][j]);
        float tim  = sigmoidf_(t[rg][j] + bgc);
        float vic  = sigmoidf_(v[rg][j] + cvc);
        float sc   = scoresL[r * 64 + c];
        float w    = gate * sc * tim;
        wLT[c * 36 + r] = w;
        *(bf16_t*)((char*)wbL + ((r * 128 + c * 2) ^ ((r & 7) << 4))) = (bf16_t)w;
        float pv = vic * sc;
        pv += __shfl_xor(pv, 1); pv += __shfl_xor(pv, 2);
        pv += __shfl_xor(pv, 4); pv += __shfl_xor(pv, 8);
        if (lr == 0) vpL[r * 4 + wq] = pv;
      }
  }
  __syncthreads();

  // vp
  if (tid < 32) {
    float s = vpL[tid * 4 + 0] + vpL[tid * 4 + 1] + vpL[tid * 4 + 2] + vpL[tid * 4 + 3];
    out[VP_OFF + tb + tid] = s;
  }
  // wT [m][tok] -> ws, coalesced 32B chunks
  {
    int m = tid >> 2, r0 = (tid & 3) * 8;
    float4 v0 = *(const float4*)&wLT[m * 36 + r0];
    float4 v1 = *(const float4*)&wLT[m * 36 + r0 + 4];
    *(float4*)&wT[m * 8192 + tb + r0] = v0;
    *(float4*)&wT[m * 8192 + tb + r0 + 4] = v1;
  }
  // sbias = w @ (bt+char) (full 128 e)
  #pragma unroll
  for (int cg = 0; cg < 2; ++cg) {
    int eg = wq * 32 + cg * 16 + lr;
    f32x4 s[2] = {{0,0,0,0},{0,0,0,0}};
    #pragma unroll
    for (int ks = 0; ks < 2; ++ks) {
      int k0 = ks * 32 + lk;
      bf16x8 b = *(const bf16x8*)(bct + eg * 64 + k0);
      #pragma unroll
      for (int rg = 0; rg < 2; ++rg) {
        int r = rg * 16 + lr;
        bf16x8 a = *(const bf16x8*)((char*)wbL + ((r * 128 + k0 * 2) ^ ((r & 7) << 4)));
        s[rg] = mfma16(a, b, s[rg]);
      }
    }
    #pragma unroll
    for (int rg = 0; rg < 2; ++rg)
      #pragma unroll
      for (int j = 0; j < 4; ++j)
        sbOut[(tb + rg * 16 + lj4 + j) * 128 + eg] = s[rg][j];
  }
}

// ---------------------------------------------------------------- kernel M (mechanisms)
__device__ __forceinline__ void loadF4(bf16x8 (&F)[4], const char* bbase, int m) {
  const char* p = bbase + m * 32768;
  F[0] = *(const bf16x8*)(p);
  F[1] = *(const bf16x8*)(p + 8192);
  F[2] = *(const bf16x8*)(p + 16384);
  F[3] = *(const bf16x8*)(p + 24576);
}

__device__ __forceinline__ void loadG(bf16x8 (&F)[4][4], const char* bbase, int mg) {
  #pragma unroll
  for (int j = 0; j < 4; ++j) loadF4(F[j], bbase, mg + j);
}

// one 4-m group: 8 rg x (4 LDS A-reads reused over 4 m) -> 128 MFMA + 32 fmac4
__device__ __forceinline__ void groupStep(const bf16x8 (&F)[4][4], int mg,
                                          const bf16_t* xL, const float* wmT,
                                          f32x4 (&acc)[8], int lr, int lg, int lj4) {
  #pragma unroll
  for (int rg = 0; rg < 8; ++rg) {
    const int r = rg * 16 + lr;
    const int rx = (r & 7) << 4;
    bf16x8 a0 = *(const bf16x8*)((const char*)xL + ((r * 256 +   0 + lg * 16) ^ rx));
    bf16x8 a1 = *(const bf16x8*)((const char*)xL + ((r * 256 +  64 + lg * 16) ^ rx));
    bf16x8 a2 = *(const bf16x8*)((const char*)xL + ((r * 256 + 128 + lg * 16) ^ rx));
    bf16x8 a3 = *(const bf16x8*)((const char*)xL + ((r * 256 + 192 + lg * 16) ^ rx));
    #pragma unroll
    for (int J = 0; J < 4; ++J) {
      f32x4 y = {0.f, 0.f, 0.f, 0.f};
      y = mfma16(a0, F[J][0], y);
      y = mfma16(a1, F[J][1], y);
      y = mfma16(a2, F[J][2], y);
      y = mfma16(a3, F[J][3], y);
      f32x4 wv = *(const f32x4*)(wmT + (mg + J) * 132 + rg * 16 + lj4);
      #pragma unroll
      for (int jj = 0; jj < 4; ++jj)
        acc[rg][jj] += wv[jj] * y[jj];
    }
  }
}

__global__ __launch_bounds__(512, 2) void kmech(
    const float* __restrict__ x, char* __restrict__ ws)
{
  __shared__ char sm[66560];
  bf16_t* xL  = (bf16_t*)sm;              // [128][128] bf16 swz, 32 KB
  float*  wmT = (float*)(sm + 32768);     // [64 m][132] f32, 33.8 KB
  float*  scr = (float*)sm;               // combine scratch (reuse), 6 x 8448 B

  const int tid = threadIdx.x;
  const int lane = tid & 63, wid = tid >> 6;
  const int es = wid & 1;                 // e-16col within slice
  const int mq = wid >> 1;                // m-quarter (16 m)
  const int tile = blockIdx.x >> 2, esl = blockIdx.x & 3;
  const int tb = tile * 128;
  const int lr = lane & 15, lg = lane >> 4;
  const int lj4 = lg * 4;
  const int eg = esl * 32 + es * 16 + lr; // global e col

  // stage xL (swizzled bf16)
  {
    int r = tid >> 2, c0 = (tid & 3) * 32;
    const float* xr = x + (tb + r) * 128 + c0;
    #pragma unroll
    for (int k = 0; k < 4; ++k) {
      bf16x8 v = cvt8(*(const float4*)(xr + k * 8), *(const float4*)(xr + k * 8 + 4));
      *(bf16x8*)((char*)xL + ((r * 256 + (c0 + k * 8) * 2) ^ ((r & 7) << 4))) = v;
    }
  }
  // stage wmT [m][t]
  {
    int m = tid >> 3, t0 = (tid & 7) * 16;
    const float* src = (const float*)(ws + WS_WT) + m * 8192 + tb + t0;
    #pragma unroll
    for (int k = 0; k < 4; ++k)
      *(float4*)&wmT[m * 132 + t0 + k * 4] = *(const float4*)(src + k * 4);
  }
  // acc init: mq0 carries sbias, others zero
  f32x4 acc[8];
  if (mq == 0) {
    const float* sb = (const float*)(ws + WS_SBIAS);
    #pragma unroll
    for (int rg = 0; rg < 8; ++rg)
      #pragma unroll
      for (int j = 0; j < 4; ++j)
        acc[rg][j] = sb[(tb + rg * 16 + lj4 + j) * 128 + eg];
  } else {
    #pragma unroll
    for (int rg = 0; rg < 8; ++rg) acc[rg] = (f32x4){0.f, 0.f, 0.f, 0.f};
  }
  __syncthreads();

  const char* bbase = (const char*)(ws + WS_WTT) + (size_t)((eg * 32 + lg * 8) * 2);
  const int m0 = mq * 16;

  bf16x8 FA[4][4], FB[4][4];
  loadG(FA, bbase, m0);
  loadG(FB, bbase, m0 + 4);
  groupStep(FA, m0,      xL, wmT, acc, lr, lg, lj4);
  loadG(FA, bbase, m0 + 8);
  groupStep(FB, m0 + 4,  xL, wmT, acc, lr, lg, lj4);
  loadG(FB, bbase, m0 + 12);
  groupStep(FA, m0 + 8,  xL, wmT, acc, lr, lg, lj4);
  groupStep(FB, m0 + 12, xL, wmT, acc, lr, lg, lj4);

  // combine 4 mq-partials (2 barriers), then mq0 writes sel
  __syncthreads();
  if (mq != 0) {
    float* buf = scr + (es * 3 + mq - 1) * 2112;   // [16 e][132] f32
    #pragma unroll
    for (int rg = 0; rg < 8; ++rg)
      *(f32x4*)&buf[lr * 132 + rg * 16 + lj4] = acc[rg];
  }
  __syncthreads();
  if (mq == 0) {
    float* sel = (float*)(ws + WS_SEL);
    const float* b0 = scr + (es * 3 + 0) * 2112;
    const float* b1 = scr + (es * 3 + 1) * 2112;
    const float* b2 = scr + (es * 3 + 2) * 2112;
    #pragma unroll
    for (int rg = 0; rg < 8; ++rg) {
      f32x4 v = acc[rg];
      f32x4 p0 = *(const f32x4*)&b0[lr * 132 + rg * 16 + lj4];
      f32x4 p1 = *(const f32x4*)&b1[lr * 132 + rg * 16 + lj4];
      f32x4 p2 = *(const f32x4*)&b2[lr * 132 + rg * 16 + lj4];
      #pragma unroll
      for (int j = 0; j < 4; ++j) {
        float o = v[j] + p0[j] + p1[j] + p2[j];
        sel[(tb + rg * 16 + lj4 + j) * 128 + eg] = o;
      }
    }
  }
}

// ---------------------------------------------------------------- kernel D (integrate)
__global__ __launch_bounds__(256) void kinteg(
    const float* __restrict__ x, const float* __restrict__ bi,
    const char* __restrict__ ws, float* __restrict__ out)
{
  const int tid = threadIdx.x;
  const int lane = tid & 63, wq = tid >> 6;
  const int tb = blockIdx.x * 32;
  const int lr = lane & 15, lg = lane >> 4;
  const int lk = lg * 8, lj4 = lg * 4;
  const bf16_t* Wit = (const bf16_t*)(ws + WS_WIT);
  const float* sel = (const float*)(ws + WS_SEL);

  bf16x8 aF[2][8];
  #pragma unroll
  for (int rg = 0; rg < 2; ++rg) {
    int t = tb + rg * 16 + lr;
    #pragma unroll
    for (int ks = 0; ks < 4; ++ks) {
      const float* src = x + t * 128 + ks * 32 + lk;
      aF[rg][ks] = cvt8(*(const float4*)src, *(const float4*)(src + 4));
    }
    #pragma unroll
    for (int ks = 0; ks < 4; ++ks) {
      const float* src = sel + t * 128 + ks * 32 + lk;
      aF[rg][4 + ks] = cvt8(*(const float4*)src, *(const float4*)(src + 4));
    }
  }
  #pragma unroll
  for (int cg = 0; cg < 2; ++cg) {
    int c = wq * 32 + cg * 16 + lr;
    f32x4 a0 = {0,0,0,0}, a1 = {0,0,0,0};
    #pragma unroll
    for (int ks = 0; ks < 8; ++ks) {
      bf16x8 b = *(const bf16x8*)(Wit + c * 256 + ks * 32 + lk);
      a0 = mfma16(aF[0][ks], b, a0);
      a1 = mfma16(aF[1][ks], b, a1);
    }
    float bb = bi[c];
    #pragma unroll
    for (int j = 0; j < 4; ++j) {
      out[(tb + lj4 + j) * 128 + c] = a0[j] + bb;
      out[(tb + 16 + lj4 + j) * 128 + c] = a1[j] + bb;
    }
  }
}

// ---------------------------------------------------------------- launch
extern "C" void kernel_launch(void* const* d_in, const int* in_sizes, int n_in,
                              void* d_out, int out_size, void* d_ws, size_t ws_size,
                              hipStream_t stream)
{
  (void)in_sizes; (void)n_in; (void)out_size; (void)ws_size;
  const float* x   = (const float*)d_in[0];
  const float* ctx = (const float*)d_in[1];
  const float* Wt  = (const float*)d_in[2];
  const float* bt  = (const float*)d_in[3];
  const float* ch  = (const float*)d_in[4];
  const float* Wg  = (const float*)d_in[5];
  const float* bg  = (const float*)d_in[6];
  const float* Wv  = (const float*)d_in[7];
  const float* bv  = (const float*)d_in[8];
  const float* O   = (const float*)d_in[9];
  const float* W1  = (const float*)d_in[10];
  const float* b1  = (const float*)d_in[11];
  const float* W2  = (const float*)d_in[12];
  const float* b2  = (const float*)d_in[13];
  const float* Wi  = (const float*)d_in[14];
  const float* bi  = (const float*)d_in[15];
  float* out = (float*)d_out;
  char* ws = (char*)d_ws;

  kprep<<<186, 256, 0, stream>>>(Wt, bt, ch, Wg, Wv, bv, O, W1, W2, Wi, ws);
  kselect<<<256, 256, 0, stream>>>(x, ctx, b1, b2, bg, ws, out);
  kmech<<<256, 512, 0, stream>>>(x, ws);
  kinteg<<<256, 256, 0, stream>>>(x, bi, ws, out);
}